// Round 6
// baseline (166.662 us; speedup 1.0000x reference)
//
#include <hip/hip_runtime.h>

#define N_NODES 50000
#define N_EDGES 500000
#define D 128
#define FXS 4194304.0f   // 2^22 fixed-point scale for weighted degree
#define CAP 64           // fixed slots per node; deg ~ Poisson(10), P(deg>64) ~ 1e-40

typedef unsigned long long u64;

// ---- pass 1 (fused fill): one 64-bit atomic per edge -> slot + degree sum;
// write (src, ew) straight into the node's fixed-capacity bin.
__global__ void pass1_kernel(const int* __restrict__ src, const int* __restrict__ dst,
                             const float* __restrict__ ew,
                             u64* __restrict__ degcnt, int2* __restrict__ pairs) {
    int e = blockIdx.x * blockDim.x + threadIdx.x;
    if (e < N_EDGES) {
        int d = dst[e];
        float w = ew[e];
        unsigned fx = __float2uint_rn(w * FXS);
        u64 old = atomicAdd(&degcnt[d], (1ull << 32) | (u64)fx);
        int slot = (int)(old >> 32);
        if (slot < CAP)   // safety clamp; never taken for this graph
            pairs[d * CAP + slot] = make_int2(src[e], __float_as_int(w));
    }
}

// ---- fused: v = W1@(W2@Wf), c1 = b1.(W2@Wf), c0 = b2.Wf + bf (per-block preamble),
// then grid-stride one-wave-per-node: t[n] = x[n,:].v ; epilogue unpacks degcnt ->
// dinv[n], cnt[n], tw[n] = dinv[n]*t[n].
__global__ void gemv_kernel(const float* __restrict__ x,
                            const float* __restrict__ W1, const float* __restrict__ W2,
                            const float* __restrict__ b1, const float* __restrict__ b2,
                            const float* __restrict__ Wf, const float* __restrict__ bf,
                            const u64* __restrict__ degcnt,
                            float* __restrict__ dinv, float* __restrict__ tw,
                            int* __restrict__ cntv, float* __restrict__ consts) {
    __shared__ float u[D];
    __shared__ float vs[D];
    const int t = threadIdx.x;
    if (t < D) {
        float a = 0.f;
#pragma unroll 8
        for (int j = 0; j < D; ++j) a += W2[t * D + j] * Wf[j];
        u[t] = a;
    }
    __syncthreads();
    if (t < D) {
        float a = 0.f;
#pragma unroll 8
        for (int k = 0; k < D; ++k) a += W1[t * D + k] * u[k];
        vs[t] = a;
    }
    __syncthreads();
    if (blockIdx.x == 0) {
        if (t == 0) {
            float c = 0.f;
            for (int k = 0; k < D; ++k) c += b1[k] * u[k];
            consts[0] = c;
        } else if (t == 1) {
            float c = bf[0];
            for (int k = 0; k < D; ++k) c += b2[k] * Wf[k];
            consts[1] = c;
        }
    }
    const int lane = t & 63;
    const int wv = t >> 6;
    for (int n = blockIdx.x * 4 + wv; n < N_NODES; n += gridDim.x * 4) {
        float2 xv = ((const float2*)(x + (size_t)n * D))[lane];
        float a = xv.x * vs[lane * 2] + xv.y * vs[lane * 2 + 1];
#pragma unroll
        for (int off = 32; off > 0; off >>= 1) a += __shfl_xor(a, off);
        if (lane == 0) {
            u64 dc = degcnt[n];
            int c = (int)(dc >> 32);
            float deg = (float)(unsigned)(dc & 0xffffffffu) * (1.0f / FXS);
            float di = rsqrtf(deg + 1.0f);
            dinv[n] = di;
            cntv[n] = (c < CAP) ? c : CAP;
            tw[n] = di * a;
        }
    }
}

// ---- s-pass: sw[n] = dinv[n] * ( dinv[n]*(sum ew*tw[src] + tw[n]) + c1 )  (8 lanes/node)
__global__ void gather_s_kernel(const float* __restrict__ tw, const float* __restrict__ dinv,
                                const int* __restrict__ cntv, const int2* __restrict__ pairs,
                                const float* __restrict__ consts, float* __restrict__ sw) {
    int tid = threadIdx.x;
    int n = blockIdx.x * 32 + (tid >> 3);
    int l = tid & 7;
    if (n >= N_NODES) return;
    int cnt = cntv[n];
    const int2* row = pairs + (size_t)n * CAP;
    float acc = 0.f;
    for (int i = l; i < cnt; i += 8) {
        int2 p = row[i];
        acc += __int_as_float(p.y) * tw[p.x];
    }
    acc += __shfl_xor(acc, 1);
    acc += __shfl_xor(acc, 2);
    acc += __shfl_xor(acc, 4);
    if (l == 0) {
        float di = dinv[n];
        float s = di * (acc + tw[n]) + consts[0];
        sw[n] = di * s;
    }
}

// ---- z-pass: out[n] = sigmoid( dinv[n]*(sum ew*sw[src] + sw[n]) + c0 ) * 10
__global__ void gather_z_kernel(const float* __restrict__ sw, const float* __restrict__ dinv,
                                const int* __restrict__ cntv, const int2* __restrict__ pairs,
                                const float* __restrict__ consts, float* __restrict__ out) {
    int tid = threadIdx.x;
    int n = blockIdx.x * 32 + (tid >> 3);
    int l = tid & 7;
    if (n >= N_NODES) return;
    int cnt = cntv[n];
    const int2* row = pairs + (size_t)n * CAP;
    float acc = 0.f;
    for (int i = l; i < cnt; i += 8) {
        int2 p = row[i];
        acc += __int_as_float(p.y) * sw[p.x];
    }
    acc += __shfl_xor(acc, 1);
    acc += __shfl_xor(acc, 2);
    acc += __shfl_xor(acc, 4);
    if (l == 0) {
        float di = dinv[n];
        float z = di * (acc + sw[n]) + consts[1];
        out[n] = 10.0f / (1.0f + expf(-z));
    }
}

extern "C" void kernel_launch(void* const* d_in, const int* in_sizes, int n_in,
                              void* d_out, int out_size, void* d_ws, size_t ws_size,
                              hipStream_t stream) {
    const float* x  = (const float*)d_in[0];
    const int*   ei = (const int*)d_in[1];
    const float* ew = (const float*)d_in[2];
    const float* W1 = (const float*)d_in[3];
    const float* b1 = (const float*)d_in[4];
    const float* W2 = (const float*)d_in[5];
    const float* b2 = (const float*)d_in[6];
    const float* Wf = (const float*)d_in[7];
    const float* bf = (const float*)d_in[8];
    const int* srcv = ei;
    const int* dstv = ei + N_EDGES;
    float* out = (float*)d_out;

    char* p = (char*)d_ws;
    auto alloc = [&](size_t bytes) { void* r = (void*)p; p += (bytes + 255) & ~(size_t)255; return r; };
    u64*   degcnt = (u64*)alloc((size_t)N_NODES * 8);
    float* dinv   = (float*)alloc(N_NODES * 4);
    int*   cntv   = (int*)alloc(N_NODES * 4);
    float* tw     = (float*)alloc(N_NODES * 4);
    float* sw     = (float*)alloc(N_NODES * 4);
    float* consts = (float*)alloc(2 * 4);
    int2*  pairs  = (int2*)alloc((size_t)N_NODES * CAP * 8);   // 25.6 MB

    const int EB = (N_EDGES + 255) / 256;

    hipMemsetAsync(degcnt, 0, (size_t)N_NODES * 8, stream);

    // atomic slot assignment + direct bin fill (one kernel)
    pass1_kernel<<<EB, 256, 0, stream>>>(srcv, dstv, ew, degcnt, pairs);

    // weight collapse + t = x@v + dinv/cnt/tw unpack (one kernel)
    gemv_kernel<<<256, 256, 0, stream>>>(x, W1, W2, b1, b2, Wf, bf, degcnt,
                                         dinv, tw, cntv, consts);

    // two scalar aggregation rounds
    gather_s_kernel<<<(N_NODES + 31) / 32, 256, 0, stream>>>(tw, dinv, cntv, pairs, consts, sw);
    gather_z_kernel<<<(N_NODES + 31) / 32, 256, 0, stream>>>(sw, dinv, cntv, pairs, consts, out);
}

// Round 7
// 137.387 us; speedup vs baseline: 1.2131x; 1.2131x over previous
//
#include <hip/hip_runtime.h>

#define N_NODES 50000
#define N_EDGES 500000
#define D 128
#define FXS 4194304.0f   // 2^22 fixed-point scale for weighted degree
#define CAP 64           // fixed slots per node; deg ~ Poisson(10), max-deg ~ 30

typedef unsigned long long u64;

// ---- pass 1 (fused fill + weight collapse):
// blocks [0, EB): one 64-bit atomic per edge -> slot + degree sum; write (src, ew)
//                 straight into the node's fixed-capacity bin.
// block EB:       v = W1@(W2@Wf), c1 = b1.(W2@Wf), c0 = b2.Wf + bf  (overlapped)
__global__ void pass1_kernel(const int* __restrict__ src, const int* __restrict__ dst,
                             const float* __restrict__ ew,
                             const float* __restrict__ W1, const float* __restrict__ W2,
                             const float* __restrict__ b1, const float* __restrict__ b2,
                             const float* __restrict__ Wf, const float* __restrict__ bf,
                             u64* __restrict__ degcnt, int2* __restrict__ pairs,
                             float* __restrict__ v, float* __restrict__ consts,
                             int eb) {
    if ((int)blockIdx.x == eb) {
        __shared__ float u[D];
        int t = threadIdx.x;
        if (t < D) {
            float a = 0.f;
#pragma unroll 8
            for (int j = 0; j < D; ++j) a += W2[t * D + j] * Wf[j];
            u[t] = a;
        }
        __syncthreads();
        if (t < D) {
            float a = 0.f;
#pragma unroll 8
            for (int k = 0; k < D; ++k) a += W1[t * D + k] * u[k];
            v[t] = a;
        }
        if (t == 0) {
            float c = 0.f;
            for (int k = 0; k < D; ++k) c += b1[k] * u[k];
            consts[0] = c;
        } else if (t == 1) {
            float c = bf[0];
            for (int k = 0; k < D; ++k) c += b2[k] * Wf[k];
            consts[1] = c;
        }
        return;
    }
    int e = blockIdx.x * blockDim.x + threadIdx.x;
    if (e < N_EDGES) {
        int d = dst[e];
        float w = ew[e];
        unsigned fx = __float2uint_rn(w * FXS);
        u64 old = atomicAdd(&degcnt[d], (1ull << 32) | (u64)fx);
        int slot = (int)(old >> 32);
        if (slot < CAP)   // safety clamp; never taken for this graph
            pairs[d * CAP + slot] = make_int2(src[e], __float_as_int(w));
    }
}

// ---- gemv: one wave per node, t[n] = x[n,:].v ; epilogue unpacks degcnt ->
// dinv[n], cnt[n], tw[n] = dinv[n]*t[n].
__global__ void gemv_kernel(const float* __restrict__ x, const float* __restrict__ v,
                            const u64* __restrict__ degcnt,
                            float* __restrict__ dinv, float* __restrict__ tw,
                            int* __restrict__ cntv) {
    __shared__ float vs[D];
    const int t = threadIdx.x;
    if (t < D) vs[t] = v[t];
    __syncthreads();
    const int lane = t & 63;
    const int n = blockIdx.x * 4 + (t >> 6);   // 50000 = 12500*4, exact
    float2 xv = ((const float2*)(x + (size_t)n * D))[lane];
    float a = xv.x * vs[lane * 2] + xv.y * vs[lane * 2 + 1];
#pragma unroll
    for (int off = 32; off > 0; off >>= 1) a += __shfl_xor(a, off);
    if (lane == 0) {
        u64 dc = degcnt[n];
        int c = (int)(dc >> 32);
        float deg = (float)(unsigned)(dc & 0xffffffffu) * (1.0f / FXS);
        float di = rsqrtf(deg + 1.0f);
        dinv[n] = di;
        cntv[n] = (c < CAP) ? c : CAP;
        tw[n] = di * a;
    }
}

// ---- s-pass: sw[n] = dinv[n] * ( dinv[n]*(sum ew*tw[src] + tw[n]) + c1 )  (8 lanes/node)
__global__ void gather_s_kernel(const float* __restrict__ tw, const float* __restrict__ dinv,
                                const int* __restrict__ cntv, const int2* __restrict__ pairs,
                                const float* __restrict__ consts, float* __restrict__ sw) {
    int tid = threadIdx.x;
    int n = blockIdx.x * 32 + (tid >> 3);
    int l = tid & 7;
    if (n >= N_NODES) return;
    int cnt = cntv[n];
    const int2* row = pairs + (size_t)n * CAP;
    float acc = 0.f;
    for (int i = l; i < cnt; i += 8) {
        int2 p = row[i];
        acc += __int_as_float(p.y) * tw[p.x];
    }
    acc += __shfl_xor(acc, 1);
    acc += __shfl_xor(acc, 2);
    acc += __shfl_xor(acc, 4);
    if (l == 0) {
        float di = dinv[n];
        float s = di * (acc + tw[n]) + consts[0];
        sw[n] = di * s;
    }
}

// ---- z-pass: out[n] = sigmoid( dinv[n]*(sum ew*sw[src] + sw[n]) + c0 ) * 10
__global__ void gather_z_kernel(const float* __restrict__ sw, const float* __restrict__ dinv,
                                const int* __restrict__ cntv, const int2* __restrict__ pairs,
                                const float* __restrict__ consts, float* __restrict__ out) {
    int tid = threadIdx.x;
    int n = blockIdx.x * 32 + (tid >> 3);
    int l = tid & 7;
    if (n >= N_NODES) return;
    int cnt = cntv[n];
    const int2* row = pairs + (size_t)n * CAP;
    float acc = 0.f;
    for (int i = l; i < cnt; i += 8) {
        int2 p = row[i];
        acc += __int_as_float(p.y) * sw[p.x];
    }
    acc += __shfl_xor(acc, 1);
    acc += __shfl_xor(acc, 2);
    acc += __shfl_xor(acc, 4);
    if (l == 0) {
        float di = dinv[n];
        float z = di * (acc + sw[n]) + consts[1];
        out[n] = 10.0f / (1.0f + expf(-z));
    }
}

extern "C" void kernel_launch(void* const* d_in, const int* in_sizes, int n_in,
                              void* d_out, int out_size, void* d_ws, size_t ws_size,
                              hipStream_t stream) {
    const float* x  = (const float*)d_in[0];
    const int*   ei = (const int*)d_in[1];
    const float* ew = (const float*)d_in[2];
    const float* W1 = (const float*)d_in[3];
    const float* b1 = (const float*)d_in[4];
    const float* W2 = (const float*)d_in[5];
    const float* b2 = (const float*)d_in[6];
    const float* Wf = (const float*)d_in[7];
    const float* bf = (const float*)d_in[8];
    const int* srcv = ei;
    const int* dstv = ei + N_EDGES;
    float* out = (float*)d_out;

    char* p = (char*)d_ws;
    auto alloc = [&](size_t bytes) { void* r = (void*)p; p += (bytes + 255) & ~(size_t)255; return r; };
    u64*   degcnt = (u64*)alloc((size_t)N_NODES * 8);
    float* dinv   = (float*)alloc(N_NODES * 4);
    int*   cntv   = (int*)alloc(N_NODES * 4);
    float* tw     = (float*)alloc(N_NODES * 4);
    float* sw     = (float*)alloc(N_NODES * 4);
    float* v      = (float*)alloc(D * 4);
    float* consts = (float*)alloc(2 * 4);
    int2*  pairs  = (int2*)alloc((size_t)N_NODES * CAP * 8);   // 25.6 MB

    const int EB = (N_EDGES + 255) / 256;   // 1954

    hipMemsetAsync(degcnt, 0, (size_t)N_NODES * 8, stream);

    // atomic slot assignment + direct bin fill + (extra block) weight collapse
    pass1_kernel<<<EB + 1, 256, 0, stream>>>(srcv, dstv, ew, W1, W2, b1, b2, Wf, bf,
                                             degcnt, pairs, v, consts, EB);

    // t = x@v ; unpack degcnt -> dinv/cnt, tw = dinv*t   (full-size grid this time)
    gemv_kernel<<<N_NODES / 4, 256, 0, stream>>>(x, v, degcnt, dinv, tw, cntv);

    // two scalar aggregation rounds
    gather_s_kernel<<<(N_NODES + 31) / 32, 256, 0, stream>>>(tw, dinv, cntv, pairs, consts, sw);
    gather_z_kernel<<<(N_NODES + 31) / 32, 256, 0, stream>>>(sw, dinv, cntv, pairs, consts, out);
}